// Round 7
// baseline (340.712 us; speedup 1.0000x reference)
//
#include <hip/hip_runtime.h>
#include <math.h>

// FlowMatchingLoss: B=8, M=K=2048. Log-domain pre-scaled by log2e (hw exp2/log2).
//   K_log' = sc_b * c,  sc_b = -20*log2e/(cmax_b+1e-8)
// Round-7: same fused persistent kernel as round 6, but PLAIN launch (the
// cooperative API rejected the launch -> output never written). Co-residency
// of all 512 blocks is guaranteed by resource arithmetic:
//   __launch_bounds__(512,4) => VGPR<=128 => 2 blocks/CU (reg file)
//   LDS 41KB => 3 blocks/CU; 8 waves/block => 4 blocks/CU (wave slots)
//   => capacity exactly 2/CU x 256 CU = 512 blocks, all resident at dispatch.
// Custom 2-level grid barrier (agent-scope fences handle cross-XCD L2).

#define LOG2E 1.4426950408889634f
#define TAU   0.95238095238095238f     // 1/(1+0.05)
#define NEG20LOG2E (-28.853900817779268f)

// workspace layout, 4-byte units
enum : int {
  OFF_PA4   = 0,        // B*M float4: x0.xyz, |x0|^2
  OFF_PB4   = 65536,    // B*K float4: xgt.xyz, |xgt|^2
  OFF_A     = 131072,   // a = sigmoid(10*tanh(alpha/10))
  OFF_LA2   = 147456,   // log2(max(a,1e-30))
  OFF_LU    = 163840,   // log_u * log2e
  OFF_LV    = 180224,   // log_v * log2e
  OFF_CPART = 196608,   // 512 per-block cmax partials (64/batch)
  OFF_SUMAP = 197120,   // 256 per-wave sum(a) partials (32/batch)
  OFF_SWP   = 197376,   // 256 per-wave sum(w)
  OFF_SEWP  = 197632,   // 256 per-wave sum(w*err)
  OFF_FPART = 197888,   // 3*512 final partials (bce, sum_pi, sum_pi*klog)
  OFF_BAR   = 199424,   // barrier: 32 group ctrs stride 32 (=1024) + root @1024
  OFF_END   = 200512
};

__device__ __forceinline__ float fexp2(float x){ return __builtin_amdgcn_exp2f(x); }
__device__ __forceinline__ float flog2(float x){ return __builtin_amdgcn_logf(x); }

__device__ __forceinline__ float wave_sum(float v){
  #pragma unroll
  for(int m=32;m;m>>=1) v += __shfl_xor(v,m,64);
  return v;
}
__device__ __forceinline__ float wave_max(float v){
  #pragma unroll
  for(int m=32;m;m>>=1) v = fmaxf(v,__shfl_xor(v,m,64));
  return v;
}

// two-level grid barrier: 32 group counters (16 blocks each) -> 1 root.
// Monotonic across phases; zeroed by k_init each launch. All 512 blocks are
// co-resident by the resource arithmetic above.
__device__ __forceinline__ void gbar(unsigned* bar, int phase, int blk){
  __syncthreads();
  if(threadIdx.x == 0){
    __threadfence();                               // release (L2 wb for XCD)
    unsigned* grp  = bar + (blk & 31)*32;
    unsigned* root = bar + 1024;
    const unsigned v = __hip_atomic_fetch_add(grp, 1u, __ATOMIC_RELAXED,
                                              __HIP_MEMORY_SCOPE_AGENT);
    if(v == (unsigned)(16*(phase+1) - 1))
      __hip_atomic_fetch_add(root, 1u, __ATOMIC_RELAXED,
                             __HIP_MEMORY_SCOPE_AGENT);
    while(__hip_atomic_load(root, __ATOMIC_RELAXED, __HIP_MEMORY_SCOPE_AGENT)
          < (unsigned)(32*(phase+1)))
      __builtin_amdgcn_s_sleep(2);
    __threadfence();                               // acquire (L2 inv)
  }
  __syncthreads();
}

__global__ __launch_bounds__(256) void k_init(float* ws){
  unsigned* bar = reinterpret_cast<unsigned*>(ws) + OFF_BAR;
  for(int i=threadIdx.x;i<1088;i+=256) bar[i] = 0u;
}

// one lse half-iteration: stage opposite side w/ lv folded, 4 rows/wave
#define LSE_PASS(ROWV, FIRSTV, PH) {                                          \
    const float4* pP = reinterpret_cast<const float4*>(                       \
                         ws + (ROWV?OFF_PB4:OFF_PA4)) + 2048*b;               \
    const float*  lo = ws + (ROWV?OFF_LV:OFF_LU) + 2048*b;                    \
    float* op = ws + (ROWV?OFF_LU:OFF_LV);                                    \
    const float4 A0=ROWV?AR[0]:AC[0], A1=ROWV?AR[1]:AC[1],                    \
                 A2=ROWV?AR[2]:AC[2], A3=ROWV?AR[3]:AC[3];                    \
    const float b0=sc*A0.w, b1=sc*A1.w, b2=sc*A2.w, b3=sc*A3.w;               \
    for(int i=tid;i<2048;i+=512){                                             \
      const float4 q = pP[i];                                                 \
      const float lvi = FIRSTV ? 0.0f : lo[i];                                \
      sB[i] = make_float4(n2sc*q.x, n2sc*q.y, n2sc*q.z, fmaf(sc,q.w,lvi));    \
    }                                                                         \
    __syncthreads();                                                          \
    float s0=0,s1=0,s2=0,s3=0;                                                \
    _Pragma("unroll 2")                                                       \
    for(int k=lane;k<2048;k+=64){                                             \
      const float4 pt = sB[k];                                                \
      s0 += fexp2(fmaf(A0.x,pt.x,fmaf(A0.y,pt.y,fmaf(A0.z,pt.z,b0+pt.w))));   \
      s1 += fexp2(fmaf(A1.x,pt.x,fmaf(A1.y,pt.y,fmaf(A1.z,pt.z,b1+pt.w))));   \
      s2 += fexp2(fmaf(A2.x,pt.x,fmaf(A2.y,pt.y,fmaf(A2.z,pt.z,b2+pt.w))));   \
      s3 += fexp2(fmaf(A3.x,pt.x,fmaf(A3.y,pt.y,fmaf(A3.z,pt.z,b3+pt.w))));   \
    }                                                                         \
    s0=wave_sum(s0); s1=wave_sum(s1); s2=wave_sum(s2); s3=wave_sum(s3);       \
    if(lane==0){                                                              \
      op[r0  ] = TAU*((ROWV?ws[OFF_LA2+r0  ]:lb2) - flog2(s0));               \
      op[r0+1] = TAU*((ROWV?ws[OFF_LA2+r0+1]:lb2) - flog2(s1));               \
      op[r0+2] = TAU*((ROWV?ws[OFF_LA2+r0+2]:lb2) - flog2(s2));               \
      op[r0+3] = TAU*((ROWV?ws[OFF_LA2+r0+3]:lb2) - flog2(s3));               \
    }                                                                         \
    gbar(bar, PH, blk);                                                       \
  }

__global__ __launch_bounds__(512,4) void k_fused(const float* __restrict__ x0,
                                                 const float* __restrict__ xgt,
                                                 const float* __restrict__ vp,
                                                 const float* __restrict__ ap,
                                                 const float* __restrict__ mxp,
                                                 float* __restrict__ ws,
                                                 float* __restrict__ out){
  __shared__ float4 sB[2048];
  __shared__ float  sL[2048];
  __shared__ float  sred[24];
  const int blk = blockIdx.x, tid = threadIdx.x, lane = tid&63, wid = tid>>6;
  const int b  = blk>>6;                          // batch (64 blocks/batch)
  const int r0 = b*2048 + (blk&63)*32 + (wid<<2); // global row of this wave
  unsigned* bar = reinterpret_cast<unsigned*>(ws) + OFF_BAR;
  float4* pA4 = reinterpret_cast<float4*>(ws+OFF_PA4);
  float4* pB4 = reinterpret_cast<float4*>(ws+OFF_PB4);

  // ---- P0: prep (blocks 0-31; one point per thread) ----
  if(blk < 32){
    const int idx = blk*512 + tid;
    const float x = x0[idx*3], y = x0[idx*3+1], z = x0[idx*3+2];
    pA4[idx] = make_float4(x,y,z, x*x+y*y+z*z);
    const float gx = xgt[idx*3], gy = xgt[idx*3+1], gz = xgt[idx*3+2];
    pB4[idx] = make_float4(gx,gy,gz, gx*gx+gy*gy+gz*gz);
    const float al = ap[idx];
    const float a = 1.0f/(1.0f + fexp2(-10.0f*tanhf(al*0.1f)*LOG2E));
    ws[OFF_A  +idx] = a;
    ws[OFF_LA2+idx] = flog2(fmaxf(a,1e-30f));
    const float w = 1.0f/(1.0f + fexp2(-al*LOG2E));
    const float tx = mxp[idx*3]-x,  ty = mxp[idx*3+1]-y,  tz = mxp[idx*3+2]-z;
    const float dx = vp[idx*3]-tx,  dy = vp[idx*3+1]-ty,  dz = vp[idx*3+2]-tz;
    const float se = dx*dx+dy*dy+dz*dz;
    const float sa = wave_sum(a), sw = wave_sum(w), sew = wave_sum(se*w);
    if(lane == 0){
      const int slot = blk*8 + wid;               // 256 slots, 32/batch
      ws[OFF_SUMAP+slot] = sa;
      ws[OFF_SWP  +slot] = sw;
      ws[OFF_SEWP +slot] = sew;
    }
  }
  gbar(bar, 0, blk);

  // ---- P1: cmax (raw points) ----
  float4 AR[4];
  #pragma unroll
  for(int r=0;r<4;r++) AR[r] = pA4[r0+r];         // persistent row fragments
  {
    const float4* pB = pB4 + 2048*b;
    for(int i=tid;i<2048;i+=512) sB[i] = pB[i];
    __syncthreads();
    float c0=0,c1=0,c2=0,c3=0;                    // init 0 == clamp at 0
    #pragma unroll 2
    for(int k=lane;k<2048;k+=64){
      const float4 pt = sB[k];
      float d;
      d = AR[0].x*pt.x+AR[0].y*pt.y+AR[0].z*pt.z; c0=fmaxf(c0, AR[0].w+pt.w-2.0f*d);
      d = AR[1].x*pt.x+AR[1].y*pt.y+AR[1].z*pt.z; c1=fmaxf(c1, AR[1].w+pt.w-2.0f*d);
      d = AR[2].x*pt.x+AR[2].y*pt.y+AR[2].z*pt.z; c2=fmaxf(c2, AR[2].w+pt.w-2.0f*d);
      d = AR[3].x*pt.x+AR[3].y*pt.y+AR[3].z*pt.z; c3=fmaxf(c3, AR[3].w+pt.w-2.0f*d);
    }
    const float cmv = wave_max(fmaxf(fmaxf(c0,c1),fmaxf(c2,c3)));
    if(lane==0) sred[wid] = cmv;
    __syncthreads();
    if(tid==0){
      float m = sred[0];
      #pragma unroll
      for(int i=1;i<8;i++) m = fmaxf(m, sred[i]);
      ws[OFF_CPART+blk] = m;
    }
  }
  gbar(bar, 1, blk);

  // ---- per-batch constants, once, kept in registers ----
  const float cm = wave_max(ws[OFF_CPART + b*64 + lane]);
  const float sc = NEG20LOG2E/(cm + 1e-8f);
  const float n2sc = -2.0f*sc;
  float sav = (lane<32) ? ws[OFF_SUMAP + b*32 + lane] : 0.0f;
  sav = wave_sum(sav);
  const float lb2 = flog2(fmaxf(sav*(1.0f/2048.0f), 1e-30f));
  float4 AC[4];
  #pragma unroll
  for(int r=0;r<4;r++) AC[r] = pB4[r0+r];         // col-side row fragments

  // ---- P2..P11: 5 Sinkhorn iterations (row, col) ----
  LSE_PASS(true,  true,  2)
  LSE_PASS(false, false, 3)
  LSE_PASS(true,  false, 4)
  LSE_PASS(false, false, 5)
  LSE_PASS(true,  false, 6)
  LSE_PASS(false, false, 7)
  LSE_PASS(true,  false, 8)
  LSE_PASS(false, false, 9)
  LSE_PASS(true,  false, 10)
  LSE_PASS(false, false, 11)

  // ---- P12: final pi pass ----
  {
    const float4* pB = pB4 + 2048*b;
    const float* lv = ws + OFF_LV + 2048*b;
    for(int i=tid;i<2048;i+=512){
      const float4 q = pB[i];
      const float lvi = lv[i];
      sB[i] = make_float4(n2sc*q.x, n2sc*q.y, n2sc*q.z, fmaf(sc,q.w,lvi));
      sL[i] = lvi;
    }
    __syncthreads();
    const float lu0=ws[OFF_LU+r0],   lu1=ws[OFF_LU+r0+1];
    const float lu2=ws[OFF_LU+r0+2], lu3=ws[OFF_LU+r0+3];
    const float bb0=fmaf(sc,AR[0].w,lu0), bb1=fmaf(sc,AR[1].w,lu1);
    const float bb2=fmaf(sc,AR[2].w,lu2), bb3=fmaf(sc,AR[3].w,lu3);
    float sp0=0,sp1=0,sp2=0,sp3=0,spa=0,spl=0;
    #pragma unroll 2
    for(int k=lane;k<2048;k+=64){
      const float4 pt = sB[k];
      const float lvk = sL[k];
      float arg, pv;
      arg=fmaf(AR[0].x,pt.x,fmaf(AR[0].y,pt.y,fmaf(AR[0].z,pt.z,bb0+pt.w)));
      pv=fexp2(arg); sp0+=pv; spa=fmaf(pv,arg,spa); spl=fmaf(pv,lvk,spl);
      arg=fmaf(AR[1].x,pt.x,fmaf(AR[1].y,pt.y,fmaf(AR[1].z,pt.z,bb1+pt.w)));
      pv=fexp2(arg); sp1+=pv; spa=fmaf(pv,arg,spa); spl=fmaf(pv,lvk,spl);
      arg=fmaf(AR[2].x,pt.x,fmaf(AR[2].y,pt.y,fmaf(AR[2].z,pt.z,bb2+pt.w)));
      pv=fexp2(arg); sp2+=pv; spa=fmaf(pv,arg,spa); spl=fmaf(pv,lvk,spl);
      arg=fmaf(AR[3].x,pt.x,fmaf(AR[3].y,pt.y,fmaf(AR[3].z,pt.z,bb3+pt.w)));
      pv=fexp2(arg); sp3+=pv; spa=fmaf(pv,arg,spa); spl=fmaf(pv,lvk,spl);
    }
    sp0=wave_sum(sp0); sp1=wave_sum(sp1); sp2=wave_sum(sp2); sp3=wave_sum(sp3);
    spa=wave_sum(spa); spl=wave_sum(spl);
    // klog = arg - lu_r - lv_k  =>  sum(pi*klog) = spa - spl - sum_r lu_r*sp_r
    float spc = spa - spl, bce = 0.0f, spt = 0.0f;
    const float lus[4]={lu0,lu1,lu2,lu3}, sps[4]={sp0,sp1,sp2,sp3};
    #pragma unroll
    for(int r=0;r<4;r++){
      const int row = r0 + r;
      spc -= lus[r]*sps[r];
      float yv = sps[r] / (ws[OFF_A+row] + 1e-8f);
      yv = fminf(fmaxf(yv,0.0f),1.0f);
      const float al = ap[row];
      bce += fmaxf(al,0.0f) - al*yv
           + 0.69314718056f*flog2(1.0f + fexp2(-fabsf(al)*LOG2E));
      spt += sps[r];
    }
    if(lane==0){ sred[wid]=bce; sred[8+wid]=spt; sred[16+wid]=spc; }
    __syncthreads();
    if(tid==0){
      float tb=0, ts=0, tc=0;
      #pragma unroll
      for(int i=0;i<8;i++){ tb+=sred[i]; ts+=sred[8+i]; tc+=sred[16+i]; }
      ws[OFF_FPART +        blk] = tb;
      ws[OFF_FPART + 512  + blk] = ts;
      ws[OFF_FPART + 1024 + blk] = tc;
    }
  }
  gbar(bar, 12, blk);

  // ---- P13: combine (block 0 only) ----
  if(blk == 0){
    float pb = ws[OFF_FPART+tid];
    float ps = ws[OFF_FPART+512+tid];
    float pc = ws[OFF_FPART+1024+tid];
    float pw = (tid<256) ? ws[OFF_SWP+tid]  : 0.0f;
    float pe = (tid<256) ? ws[OFF_SEWP+tid] : 0.0f;
    pb=wave_sum(pb); ps=wave_sum(ps); pc=wave_sum(pc);
    pw=wave_sum(pw); pe=wave_sum(pe);
    if(lane==0){
      sL[wid*5+0]=pb; sL[wid*5+1]=ps; sL[wid*5+2]=pc;
      sL[wid*5+3]=pw; sL[wid*5+4]=pe;
    }
    __syncthreads();
    if(tid==0){
      float bce=0, sp=0, spc=0, sw=0, sew=0;
      #pragma unroll
      for(int w=0;w<8;w++){
        bce+=sL[w*5+0]; sp+=sL[w*5+1]; spc+=sL[w*5+2];
        sw +=sL[w*5+3]; sew+=sL[w*5+4];
      }
      const float loss_vel  = sew / fmaxf(sw, 1.0f);
      const float loss_surv = bce / 16384.0f;
      // sum(pi*cost_n) = spc * (-ln2/20)  since klog = -20*log2e*cost_n
      const float loss_tr = (spc * (-0.03465735902799726f)) / fmaxf(sp, 1e-8f);
      out[0] = loss_vel + loss_surv + 0.1f*loss_tr;
    }
  }
}

extern "C" void kernel_launch(void* const* d_in, const int* in_sizes, int n_in,
                              void* d_out, int out_size, void* d_ws, size_t ws_size,
                              hipStream_t stream) {
  (void)in_sizes; (void)n_in; (void)out_size; (void)ws_size;
  const float* x0  = (const float*)d_in[0];
  const float* xgt = (const float*)d_in[1];
  const float* vp  = (const float*)d_in[2];
  const float* ap  = (const float*)d_in[3];
  const float* mxp = (const float*)d_in[5];   // t (d_in[4]) unused
  float* ws  = (float*)d_ws;
  float* out = (float*)d_out;

  k_init<<<1, 256, 0, stream>>>(ws);          // zero barrier counters

  k_fused<<<512, 512, 0, stream>>>(x0, xgt, vp, ap, mxp, ws, out);
}